// Round 22
// baseline (200.862 us; speedup 1.0000x reference)
//
#include <hip/hip_runtime.h>

// ---------------------------------------------------------------------------
// Sea_Attention MI355X round 22.
// Base = round 21 (verified 198.7 us). One change: dwm portion of dwmmc_k gets
// an explicit 2-row-buffer software pipeline (pure per-thread registers, no
// LDS/sync hazard class): rows loaded branch-free (clamped h), next row's
// 10-load batch issued before previous row's compute. Math identical to r5.
// ws layout (bytes):
//   qkvs bf16 [16][4096][512] @ 0      (c: q 0-127 | k 128-255 | v 256-511)
//   dwo  bf16 [16][4096][512] @ 64M
//   xbf  bf16 [16][4096][256] @ 160M
//   mr   f32  [16][512][64]   @ 192M   (row means, indexed by h)
//   mc   f32  [16][512][64]   @ 194M   (col means, indexed by w)
//   xxa  f32  [16][2][256][64] @ 196M
//   xrct f32  [16][2][64][256] @ 198M  (position-major rc output)
//   wqkv bf16 [512][256] @ 200M ; wpw [256][512]; wpr [256][256]; bqkv f32[512]
// ---------------------------------------------------------------------------

typedef short s16x8 __attribute__((ext_vector_type(8)));
typedef short s16x4 __attribute__((ext_vector_type(4)));
typedef float f32x4 __attribute__((ext_vector_type(4)));

#define OFF_QKVS 0ULL
#define OFF_DWO  67108864ULL
#define OFF_XBF  167772160ULL
#define OFF_MR   201326592ULL
#define OFF_MC   203423744ULL
#define OFF_XXA  205520896ULL
#define OFF_XRCT 207618048ULL
#define OFF_WQKV 209715200ULL
#define OFF_WPW  209977344ULL
#define OFF_WPR  210239488ULL
#define OFF_BQKV 210370560ULL

__device__ __forceinline__ float bf2f(unsigned short u) {
  unsigned int x = ((unsigned int)u) << 16;
  return __builtin_bit_cast(float, x);
}
__device__ __forceinline__ unsigned short f2bf(float f) {
  unsigned int x = __builtin_bit_cast(unsigned int, f);
  x += 0x7fffu + ((x >> 16) & 1u);   // RNE, finite inputs
  return (unsigned short)(x >> 16);
}
__device__ __forceinline__ float relu6f(float v) { return fminf(fmaxf(v, 0.f), 6.f); }

// D = A*B + D (A rows -> D rows, B cols -> D cols; verified round 1/3)
__device__ __forceinline__ void mfma16(f32x4& d, s16x8 a, s16x8 b) {
  asm("v_mfma_f32_16x16x32_bf16 %0, %1, %2, %0" : "+v"(d) : "v"(a), "v"(b));
}

// ---------------------------------------------------------------------------
// prep: bid < 4096 -> x transpose tile; bid >= 4096 -> weight pack (verified r14)
// ---------------------------------------------------------------------------
__global__ __launch_bounds__(256) void prep_k(
    const float* __restrict__ x, unsigned short* __restrict__ xbf,
    const float* __restrict__ Wq, const float* __restrict__ Wk, const float* __restrict__ Wv,
    const float* __restrict__ bq, const float* __restrict__ bk, const float* __restrict__ bv,
    const float* __restrict__ Wpw, const float* __restrict__ Wpr,
    unsigned short* __restrict__ wqkv, unsigned short* __restrict__ wpw,
    unsigned short* __restrict__ wpr, float* __restrict__ bqkv)
{
  __shared__ float tile[64][68];
  const int bid = blockIdx.x;
  const int tid = threadIdx.x;
  if (bid < 4096) {
    const int nt = bid & 63, ct = (bid >> 6) & 3, b = bid >> 8;
    const int n0 = nt * 64, c0 = ct * 64;
    #pragma unroll
    for (int p = 0; p < 4; ++p) {
      const int g = tid + p * 256;
      const int row = g >> 4, ch = g & 15;
      const float4 v = *(const float4*)&x[((size_t)b * 256 + c0 + row) * 4096 + n0 + ch * 4];
      *(float4*)&tile[row][ch * 4] = v;
    }
    __syncthreads();
    #pragma unroll
    for (int p = 0; p < 2; ++p) {
      const int g = tid + p * 256;
      const int nr = g >> 3, cc = g & 7;
      s16x8 o;
      #pragma unroll
      for (int q = 0; q < 8; ++q) o[q] = f2bf(tile[cc * 8 + q][nr]);
      *(s16x8*)&xbf[((size_t)b * 4096 + n0 + nr) * 256 + c0 + cc * 8] = o;
    }
  } else {
    const int i = (bid - 4096) * 256 + tid;
    if (i < 131072) {
      const int o = i >> 8, k = i & 255;
      float v = (o < 128) ? Wq[o * 256 + k]
              : (o < 256) ? Wk[(o - 128) * 256 + k]
                          : Wv[(o - 256) * 256 + k];
      wqkv[i] = f2bf(v);
    } else if (i < 262144) {
      const int j = i - 131072;
      wpw[j] = f2bf(Wpw[j]);
    } else if (i < 327680) {
      const int j = i - 262144;
      wpr[j] = f2bf(Wpr[j]);
    } else if (i < 328192) {
      const int o = i - 327680;
      bqkv[o] = (o < 128) ? bq[o] : (o < 256) ? bk[o - 128] : bv[o - 256];
    }
  }
}

// ---------------------------------------------------------------------------
// GEMM staging into padded LDS [rows][72] (verified layout; used by fin_k)
// ---------------------------------------------------------------------------
template <int ROWS>
__device__ __forceinline__ void stage_rows(const unsigned short* __restrict__ src,
                                           int ld, unsigned short (*S)[72], int tid)
{
  #pragma unroll
  for (int p = 0; p < ROWS / 32; ++p) {
    const int g = tid + p * 256;
    const int r = g >> 3, sl = g & 7;
    *(s16x8*)&S[r][sl * 8] = *(const s16x8*)&src[(size_t)r * ld + sl * 8];
  }
}

// one 64-K step: acc[8][2] += W-subtile(128 o) x X-subtile(32 n)  (fin_k)
__device__ __forceinline__ void compute64(const unsigned short (*As)[72],
                                          const unsigned short (*Xs)[72],
                                          f32x4 (*acc)[2], int wm, int wn, int lane)
{
  #pragma unroll
  for (int ks = 0; ks < 64; ks += 32) {
    s16x8 bF[2], aF[8];
    #pragma unroll
    for (int j = 0; j < 2; ++j)
      bF[j] = *(const s16x8*)&Xs[wn * 32 + j * 16 + (lane & 15)][ks + (lane >> 4) * 8];
    #pragma unroll
    for (int i = 0; i < 8; ++i)
      aF[i] = *(const s16x8*)&As[wm * 128 + i * 16 + (lane & 15)][ks + (lane >> 4) * 8];
    #pragma unroll
    for (int i = 0; i < 8; ++i)
      #pragma unroll
      for (int j = 0; j < 2; ++j)
        mfma16(acc[i][j], aF[i], bF[j]);
  }
}

// ---------------------------------------------------------------------------
// QKV (verified round 9): W panel LDS-resident, 4 fat n-tiles, XOR swizzle,
// X reg-prefetch, in-wave row-mean.
// ---------------------------------------------------------------------------
__global__ __launch_bounds__(256, 2) void qkv_k(
    const unsigned short* __restrict__ wqkv, const float* __restrict__ bias,
    const unsigned short* __restrict__ xbf, unsigned short* __restrict__ qkvs,
    float* __restrict__ mr)
{
  __shared__ __align__(16) unsigned short Ws[128][256];  // swizzled granules
  __shared__ __align__(16) unsigned short Xs[128][64];   // swizzled granules
  const int tid = threadIdx.x, lane = tid & 63, wave = tid >> 6;
  const int wm = wave >> 1, wn = wave & 1;
  const int bid = blockIdx.x;
  const int ng = bid & 7, mt = (bid >> 3) & 3, b = bid >> 5;
  const int row0 = mt * 128;
  const int n_base = ng * 512;
  const unsigned short* Xb = xbf + ((size_t)b * 4096 + n_base) * 256;

  s16x8 pX[4];
  #pragma unroll
  for (int p = 0; p < 4; ++p) {
    const int g = tid + p * 256, r = g >> 3, gl = g & 7;
    pX[p] = *(const s16x8*)&Xb[(size_t)r * 256 + gl * 8];
  }
  #pragma unroll
  for (int p = 0; p < 16; ++p) {
    const int g = tid + p * 256;
    const int r = g >> 5, gl = g & 31;
    *(s16x8*)&Ws[r][(gl ^ (r & 7)) * 8] =
        *(const s16x8*)&wqkv[(size_t)(row0 + r) * 256 + gl * 8];
  }

  for (int t = 0; t < 4; ++t) {
    f32x4 acc[4][4];
    #pragma unroll
    for (int i = 0; i < 4; ++i)
      #pragma unroll
      for (int j = 0; j < 4; ++j) acc[i][j] = (f32x4){0.f, 0.f, 0.f, 0.f};

    #pragma unroll
    for (int c = 0; c < 4; ++c) {
      __syncthreads();
      #pragma unroll
      for (int p = 0; p < 4; ++p) {
        const int g = tid + p * 256, r = g >> 3, gl = g & 7;
        *(s16x8*)&Xs[r][(gl ^ (r & 7)) * 8] = pX[p];
      }
      __syncthreads();
      const int ci = t * 4 + c;
      if (ci < 15) {
        const int tn = (ci + 1) >> 2, cn = (ci + 1) & 3;
        #pragma unroll
        for (int p = 0; p < 4; ++p) {
          const int g = tid + p * 256, r = g >> 3, gl = g & 7;
          pX[p] = *(const s16x8*)&Xb[(size_t)(tn * 128 + r) * 256 + cn * 64 + gl * 8];
        }
      }
      #pragma unroll
      for (int ks = 0; ks < 64; ks += 32) {
        s16x8 aF[4], bF[4];
        #pragma unroll
        for (int i = 0; i < 4; ++i) {
          const int row = wm * 64 + i * 16 + (lane & 15);
          const int kg = ((c * 64 + ks) >> 3) + (lane >> 4);
          aF[i] = *(const s16x8*)&Ws[row][(kg ^ (row & 7)) * 8];
        }
        #pragma unroll
        for (int j = 0; j < 4; ++j) {
          const int row = wn * 64 + j * 16 + (lane & 15);
          const int kg = (ks >> 3) + (lane >> 4);
          bF[j] = *(const s16x8*)&Xs[row][(kg ^ (row & 7)) * 8];
        }
        #pragma unroll
        for (int i = 0; i < 4; ++i)
          #pragma unroll
          for (int j = 0; j < 4; ++j)
            mfma16(acc[i][j], aF[i], bF[j]);
      }
    }

    const int n0 = n_base + t * 128;
    #pragma unroll
    for (int i = 0; i < 4; ++i) {
      const int o0 = row0 + wm * 64 + i * 16 + ((lane >> 4) << 2);
      const float4 b4 = *(const float4*)&bias[o0];
      const float bv[4] = {b4.x, b4.y, b4.z, b4.w};
      #pragma unroll
      for (int j = 0; j < 4; ++j) {
        const int n = n0 + wn * 64 + j * 16 + (lane & 15);
        s16x4 pk;
        pk[0] = f2bf(acc[i][j][0] + bv[0]);
        pk[1] = f2bf(acc[i][j][1] + bv[1]);
        pk[2] = f2bf(acc[i][j][2] + bv[2]);
        pk[3] = f2bf(acc[i][j][3] + bv[3]);
        *(s16x4*)&qkvs[((size_t)b * 4096 + n) * 512 + o0] = pk;
      }
      #pragma unroll
      for (int r = 0; r < 4; ++r) {
        float s = acc[i][0][r] + acc[i][1][r] + acc[i][2][r] + acc[i][3][r];
        s += __shfl_xor(s, 1);
        s += __shfl_xor(s, 2);
        s += __shfl_xor(s, 4);
        s += __shfl_xor(s, 8);
        if ((lane & 15) == 0) {
          const int o = o0 + r;
          mr[((size_t)b * 512 + o) * 64 + (n0 >> 6) + wn] = s * (1.f / 64.f) + bv[r];
        }
      }
    }
  }
}

// ---------------------------------------------------------------------------
// dwm (r5 math, 2-row-buffer pipeline) + mc (verified r11), 256-thread blocks.
// bid < 2048: dwm: b = bid>>7, h = (bid>>1)&63, whalf = bid&1;
//   thread: c0 = (tid&63)*8, w0 = ((whalf*4) + (tid>>6))*8
// bid >= 2048: mc block mbid = bid-2048 (verbatim r11).
// ---------------------------------------------------------------------------
__global__ __launch_bounds__(256, 2) void dwmmc_k(
    const unsigned short* __restrict__ qkvs, const float* __restrict__ Wdw,
    const float* __restrict__ bdw, unsigned short* __restrict__ dwo,
    float* __restrict__ mc)
{
  const int bid = blockIdx.x;
  const int tid = threadIdx.x;
  if (bid < 2048) {                       // ---- dwm ----
    const int b = bid >> 7;
    const int h = (bid >> 1) & 63;
    const int whalf = bid & 1;
    const int c0 = (tid & 63) * 8;
    const int w0 = (whalf * 4 + (tid >> 6)) * 8;
    float w9[8][9], bs[8];
    #pragma unroll
    for (int q = 0; q < 8; ++q) {
      bs[q] = bdw[c0 + q];
      #pragma unroll
      for (int j = 0; j < 9; ++j) w9[q][j] = Wdw[(c0 + q) * 9 + j];
    }
    float acc[8][8];
    #pragma unroll
    for (int w = 0; w < 8; ++w)
      #pragma unroll
      for (int q = 0; q < 8; ++q) acc[w][q] = bs[q];

    const size_t base = (size_t)b * 4096 * 512;
    const int h0 = (h > 0) ? (h - 1) : 0;     // clamped rows (loads always safe)
    const int h2 = (h < 63) ? (h + 1) : 63;
    const bool v0 = (h > 0), v2 = (h < 63);

    s16x8 rA[10], rB[10];
#define LOADROW(BUF, HH)                                                      \
    { _Pragma("unroll")                                                       \
      for (int t = 0; t < 10; ++t) {                                          \
        const int ww = w0 + t - 1;                                            \
        if ((unsigned)ww < 64u)                                               \
          BUF[t] = *(const s16x8*)&qkvs[base + (size_t)((HH) * 64 + ww) * 512 + c0]; \
        else BUF[t] = (s16x8){0, 0, 0, 0, 0, 0, 0, 0};                        \
      } }
#define COMPROW(BUF, DR)                                                      \
    { _Pragma("unroll")                                                       \
      for (int t = 0; t < 10; ++t) {                                          \
        float fv[8];                                                          \
        _Pragma("unroll")                                                     \
        for (int q = 0; q < 8; ++q) fv[q] = bf2f((unsigned short)BUF[t][q]);  \
        _Pragma("unroll")                                                     \
        for (int dc = 0; dc < 3; ++dc) {                                      \
          const int w = t - dc;                                               \
          if (w >= 0 && w < 8) {                                              \
            _Pragma("unroll")                                                 \
            for (int q = 0; q < 8; ++q)                                       \
              acc[w][q] += w9[q][(DR) * 3 + dc] * fv[q];                      \
          }                                                                   \
        }                                                                     \
      } }

    LOADROW(rA, h0)                       // row 0 batch in flight
    LOADROW(rB, h)                        // row 1 batch in flight (MLP 20)
    if (v0) COMPROW(rA, 0)                // consume row 0 (uniform guard)
    LOADROW(rA, h2)                       // row 2 batch flies under row-1 compute
    COMPROW(rB, 1)                        // row 1 always valid
    if (v2) COMPROW(rA, 2)                // consume row 2
#undef LOADROW
#undef COMPROW

    #pragma unroll
    for (int w = 0; w < 8; ++w) {
      s16x8 o8;
      #pragma unroll
      for (int q = 0; q < 8; ++q) o8[q] = f2bf(relu6f(acc[w][q]));
      *(s16x8*)&dwo[base + (size_t)(h * 64 + w0 + w) * 512 + c0] = o8;
    }
  } else {                                // ---- mc (verbatim r11) ----
    const int mbid = bid - 2048;          // 0..255
    const int posq = mbid & 15, b = mbid >> 4;
    const int c0 = (tid & 63) * 8;
    const int pos = posq * 4 + (tid >> 6);
    float s[8] = {0.f, 0.f, 0.f, 0.f, 0.f, 0.f, 0.f, 0.f};
    for (int t = 0; t < 64; ++t) {
      const s16x8 v = *(const s16x8*)&qkvs[((size_t)b * 4096 + t * 64 + pos) * 512 + c0];
      #pragma unroll
      for (int q = 0; q < 8; ++q) s[q] += bf2f((unsigned short)v[q]);
    }
    #pragma unroll
    for (int q = 0; q < 8; ++q)
      mc[((size_t)b * 512 + c0 + q) * 64 + pos] = s[q] * (1.f / 64.f);
  }
}

// ---------------------------------------------------------------------------
// fused final (round-7 verified): pw = Wpw.dwo+bpw ; pr = Wpr.relu6(v+xr+xc)+bpr
// out[o][n] = h_sig(pr)*pw. T14 prefetch of X (loop 1) and v (loop 2).
// ---------------------------------------------------------------------------
__global__ __launch_bounds__(256, 2) void fin_k(
    const unsigned short* __restrict__ wpw, const float* __restrict__ bpw,
    const unsigned short* __restrict__ wpr, const float* __restrict__ bpr,
    const unsigned short* __restrict__ dwo, const unsigned short* __restrict__ qkvs,
    const float* __restrict__ xrct, float* __restrict__ out)
{
  __shared__ __align__(16) unsigned short As[256][72];
  __shared__ __align__(16) unsigned short Xs[64][72];
  const int tid = threadIdx.x, lane = tid & 63, wave = tid >> 6;
  const int wm = wave >> 1, wn = wave & 1;
  const int bid = blockIdx.x;
  const int nt = bid & 63, b = bid >> 6;
  const int col0 = nt * 64;                 // h = nt, w = n-local

  f32x4 apw[8][2], apr[8][2];
  #pragma unroll
  for (int i = 0; i < 8; ++i)
    #pragma unroll
    for (int j = 0; j < 2; ++j) {
      apw[i][j] = (f32x4){0.f, 0.f, 0.f, 0.f};
      apr[i][j] = (f32x4){0.f, 0.f, 0.f, 0.f};
    }

  // ---- GEMM 1: pw = Wpw . dwo, K = 512, X prefetched ----
  const unsigned short* Xb1 = dwo + ((size_t)b * 4096 + col0) * 512;
  s16x8 pX[2];
  #pragma unroll
  for (int p = 0; p < 2; ++p) {
    const int g = tid + p * 256, r = g >> 3, sl = g & 7;
    pX[p] = *(const s16x8*)&Xb1[(size_t)r * 512 + sl * 8];
  }
  for (int k0 = 0; k0 < 512; k0 += 64) {
    stage_rows<256>(wpw + k0, 512, As, tid);       // W panel: L2-hot
    #pragma unroll
    for (int p = 0; p < 2; ++p) {
      const int g = tid + p * 256, r = g >> 3, sl = g & 7;
      *(s16x8*)&Xs[r][sl * 8] = pX[p];
    }
    __syncthreads();
    if (k0 + 64 < 512) {
      const int kn = k0 + 64;
      #pragma unroll
      for (int p = 0; p < 2; ++p) {
        const int g = tid + p * 256, r = g >> 3, sl = g & 7;
        pX[p] = *(const s16x8*)&Xb1[(size_t)r * 512 + kn + sl * 8];
      }
    }
    compute64(As, Xs, apw, wm, wn, lane);
    __syncthreads();
  }

  // ---- GEMM 2: pr = Wpr . relu6(v + xr + xc), K = 256, v prefetched ----
  const float* xr = &xrct[(((size_t)b * 2 + 0) * 64 + nt) * 256];   // block-uniform h
  const float* xc = &xrct[(((size_t)b * 2 + 1) * 64) * 256];
  const unsigned short* Vb = qkvs + ((size_t)b * 4096 + col0) * 512 + 256;
  s16x8 pV[2];
  #pragma unroll
  for (int p = 0; p < 2; ++p) {
    const int g = tid + p * 256, r = g >> 3, sl = g & 7;
    pV[p] = *(const s16x8*)&Vb[(size_t)r * 512 + sl * 8];
  }
  for (int k0 = 0; k0 < 256; k0 += 64) {
    stage_rows<256>(wpr + k0, 256, As, tid);
    #pragma unroll
    for (int p = 0; p < 2; ++p) {
      const int g = tid + p * 256, r = g >> 3, sl = g & 7;
      const int kk = k0 + sl * 8;
      const float4 a0 = *(const float4*)&xr[kk];
      const float4 a1 = *(const float4*)&xr[kk + 4];
      const float4 c0v = *(const float4*)&xc[(size_t)r * 256 + kk];
      const float4 c1v = *(const float4*)&xc[(size_t)r * 256 + kk + 4];
      const float ar[8] = {a0.x, a0.y, a0.z, a0.w, a1.x, a1.y, a1.z, a1.w};
      const float ac[8] = {c0v.x, c0v.y, c0v.z, c0v.w, c1v.x, c1v.y, c1v.z, c1v.w};
      s16x8 o;
      #pragma unroll
      for (int q = 0; q < 8; ++q)
        o[q] = f2bf(relu6f(bf2f((unsigned short)pV[p][q]) + ar[q] + ac[q]));
      *(s16x8*)&Xs[r][sl * 8] = o;
    }
    __syncthreads();
    if (k0 + 64 < 256) {
      const int kn = k0 + 64;
      #pragma unroll
      for (int p = 0; p < 2; ++p) {
        const int g = tid + p * 256, r = g >> 3, sl = g & 7;
        pV[p] = *(const s16x8*)&Vb[(size_t)r * 512 + kn + sl * 8];
      }
    }
    compute64(As, Xs, apr, wm, wn, lane);
    __syncthreads();
  }

  #pragma unroll
  for (int i = 0; i < 8; ++i) {
    const int o0 = wm * 128 + i * 16 + ((lane >> 4) << 2);
    const float4 bw = *(const float4*)&bpw[o0];
    const float4 bp = *(const float4*)&bpr[o0];
    const float bwv[4] = {bw.x, bw.y, bw.z, bw.w};
    const float bpv[4] = {bp.x, bp.y, bp.z, bp.w};
    #pragma unroll
    for (int j = 0; j < 2; ++j) {
      const int n = col0 + wn * 32 + j * 16 + (lane & 15);
      #pragma unroll
      for (int r = 0; r < 4; ++r) {
        const float hs = fminf(fmaxf(apr[i][j][r] + bpv[r] + 3.f, 0.f), 6.f) * (1.f / 6.f);
        out[((size_t)b * 256 + o0 + r) * 4096 + n] = hs * (apw[i][j][r] + bwv[r]);
      }
    }
  }
}

// ---------------------------------------------------------------------------
// axial attention (verified)
// ---------------------------------------------------------------------------
__global__ __launch_bounds__(256) void attn_k(
    const float* __restrict__ mr, const float* __restrict__ mc,
    const float* __restrict__ pe_rq, const float* __restrict__ pe_rk,
    const float* __restrict__ pe_cq, const float* __restrict__ pe_ck,
    float* __restrict__ xxa)
{
  __shared__ float qh[16][69], kh[16][69], vh[32][69], P[64][69];
  const int bid = blockIdx.x;
  const int hd = bid & 7, axis = (bid >> 3) & 1, b = bid >> 4;
  const float* m  = axis ? mc : mr;
  const float* pq = axis ? pe_cq : pe_rq;
  const float* pk = axis ? pe_ck : pe_rk;
  const int tid = threadIdx.x;

  #pragma unroll
  for (int p = 0; p < 4; ++p) {
    const int e = tid + p * 256;
    const int kd = e >> 6, i = e & 63;
    float srcp = 0.25f * (float)i - 0.375f;
    srcp = fminf(fmaxf(srcp, 0.f), 15.f);
    const int lo = (int)srcp;
    const int hi = min(lo + 1, 15);
    const float w = srcp - (float)lo;
    const int cq = hd * 16 + kd;
    qh[kd][i] = m[((size_t)b * 512 + cq) * 64 + i]
              + pq[cq * 16 + lo] * (1.f - w) + pq[cq * 16 + hi] * w;
    kh[kd][i] = m[((size_t)b * 512 + 128 + cq) * 64 + i]
              + pk[cq * 16 + lo] * (1.f - w) + pk[cq * 16 + hi] * w;
  }
  #pragma unroll
  for (int p = 0; p < 8; ++p) {
    const int e = tid + p * 256;
    const int d = e >> 6, j = e & 63;
    vh[d][j] = m[((size_t)b * 512 + 256 + hd * 32 + d) * 64 + j];
  }
  __syncthreads();
  {
    const int i = tid >> 2, j0 = (tid & 3) * 16;
    float qr[16];
    #pragma unroll
    for (int kd = 0; kd < 16; ++kd) qr[kd] = qh[kd][i];
    #pragma unroll
    for (int jj = 0; jj < 16; ++jj) {
      float s = 0.f;
      #pragma unroll
      for (int kd = 0; kd < 16; ++kd) s += qr[kd] * kh[kd][j0 + jj];
      P[i][j0 + jj] = s * 0.25f;
    }
  }
  __syncthreads();
  if (tid < 64) {
    float mx = -1e30f;
    for (int j = 0; j < 64; ++j) mx = fmaxf(mx, P[tid][j]);
    float sum = 0.f;
    for (int j = 0; j < 64; ++j) { const float e = __expf(P[tid][j] - mx); P[tid][j] = e; sum += e; }
    const float inv = 1.f / sum;
    for (int j = 0; j < 64; ++j) P[tid][j] *= inv;
  }
  __syncthreads();
  #pragma unroll
  for (int p = 0; p < 8; ++p) {
    const int e = tid + p * 256;
    const int d = e >> 6, i = e & 63;
    float s = 0.f;
    for (int j = 0; j < 64; ++j) s += P[i][j] * vh[d][j];
    xxa[(((size_t)(b * 2 + axis)) * 256 + hd * 32 + d) * 64 + i] = s;
  }
}

// ---------------------------------------------------------------------------
// xrct[b][axis][pos][o] = (W_row/W_col @ relu6(xxa))[o][pos] + bias[o]
// ---------------------------------------------------------------------------
__global__ __launch_bounds__(256) void rc_k(
    const float* __restrict__ xxa, const float* __restrict__ Wrow, const float* __restrict__ brow,
    const float* __restrict__ Wcol, const float* __restrict__ bcol, float* __restrict__ xrct)
{
  __shared__ float stf[256][8];
  const int bid = blockIdx.x;
  const int ic = bid & 7, axis = (bid >> 3) & 1, b = bid >> 4;
  const float* W  = axis ? Wcol : Wrow;
  const float* bi = axis ? bcol : brow;
  const int tid = threadIdx.x;
  {
    const float* srcp = xxa + (((size_t)(b * 2 + axis)) * 256 + tid) * 64 + ic * 8;
    #pragma unroll
    for (int q = 0; q < 8; ++q) stf[tid][q] = relu6f(srcp[q]);
  }
  __syncthreads();
  float acc[8] = {0.f, 0.f, 0.f, 0.f, 0.f, 0.f, 0.f, 0.f};
  for (int c = 0; c < 256; ++c) {
    const float w = W[tid * 256 + c];
    const float4 s0 = *(const float4*)&stf[c][0];
    const float4 s1 = *(const float4*)&stf[c][4];
    acc[0] += w * s0.x; acc[1] += w * s0.y; acc[2] += w * s0.z; acc[3] += w * s0.w;
    acc[4] += w * s1.x; acc[5] += w * s1.y; acc[6] += w * s1.z; acc[7] += w * s1.w;
  }
  const float bb = bi[tid];
  #pragma unroll
  for (int q = 0; q < 8; ++q)
    xrct[(((size_t)(b * 2 + axis)) * 64 + ic * 8 + q) * 256 + tid] = acc[q] + bb;
}

// ---------------------------------------------------------------------------
extern "C" void kernel_launch(void* const* d_in, const int* in_sizes, int n_in,
                              void* d_out, int out_size, void* d_ws, size_t ws_size,
                              hipStream_t stream)
{
  const float* x    = (const float*)d_in[0];
  const float* Wq   = (const float*)d_in[1];
  const float* bq   = (const float*)d_in[2];
  const float* Wk   = (const float*)d_in[3];
  const float* bk   = (const float*)d_in[4];
  const float* Wv   = (const float*)d_in[5];
  const float* bv   = (const float*)d_in[6];
  const float* Wdw  = (const float*)d_in[7];
  const float* bdw  = (const float*)d_in[8];
  const float* Wpw  = (const float*)d_in[9];
  const float* bpw  = (const float*)d_in[10];
  const float* Wrow = (const float*)d_in[11];
  const float* brow = (const float*)d_in[12];
  const float* Wcol = (const float*)d_in[13];
  const float* bcol = (const float*)d_in[14];
  const float* Wpr  = (const float*)d_in[15];
  const float* bpr  = (const float*)d_in[16];
  const float* perq = (const float*)d_in[17];
  const float* perk = (const float*)d_in[18];
  const float* pecq = (const float*)d_in[19];
  const float* peck = (const float*)d_in[20];

  char* ws = (char*)d_ws;
  unsigned short* qkvs = (unsigned short*)(ws + OFF_QKVS);
  unsigned short* dwo  = (unsigned short*)(ws + OFF_DWO);
  unsigned short* xbf  = (unsigned short*)(ws + OFF_XBF);
  float* mr   = (float*)(ws + OFF_MR);
  float* mc   = (float*)(ws + OFF_MC);
  float* xxa  = (float*)(ws + OFF_XXA);
  float* xrct = (float*)(ws + OFF_XRCT);
  unsigned short* wqkv = (unsigned short*)(ws + OFF_WQKV);
  unsigned short* wpw  = (unsigned short*)(ws + OFF_WPW);
  unsigned short* wpr  = (unsigned short*)(ws + OFF_WPR);
  float* bqkv = (float*)(ws + OFF_BQKV);

  prep_k<<<5378, 256, 0, stream>>>(x, xbf, Wq, Wk, Wv, bq, bk, bv, Wpw, Wpr,
                                   wqkv, wpw, wpr, bqkv);

  qkv_k<<<512, 256, 0, stream>>>(wqkv, bqkv, xbf, qkvs, mr);
  dwmmc_k<<<2304, 256, 0, stream>>>(qkvs, Wdw, bdw, dwo, mc);
  attn_k<<<256, 256, 0, stream>>>(mr, mc, perq, perk, pecq, peck, xxa);
  rc_k<<<256, 256, 0, stream>>>(xxa, Wrow, brow, Wcol, bcol, xrct);
  fin_k<<<1024, 256, 0, stream>>>(wpw, bpw, wpr, bpr, dwo, qkvs, xrct, (float*)d_out);
}

// Round 23
// 198.414 us; speedup vs baseline: 1.0123x; 1.0123x over previous
//
#include <hip/hip_runtime.h>

// ---------------------------------------------------------------------------
// Sea_Attention MI355X round 23 == round 19/21 VERBATIM (session best:
// 198.7 us, absmax 0.015625, reproduced twice). r22's dwm 2-row register
// pipeline regressed (+2.2 us, VGPR 92->112) and is reverted.
// Composition: prep(r14) + qkv(r9) + dwmmc(r19) + attn/rc(r1) + fin(r7).
// ws layout (bytes):
//   qkvs bf16 [16][4096][512] @ 0      (c: q 0-127 | k 128-255 | v 256-511)
//   dwo  bf16 [16][4096][512] @ 64M
//   xbf  bf16 [16][4096][256] @ 160M
//   mr   f32  [16][512][64]   @ 192M   (row means, indexed by h)
//   mc   f32  [16][512][64]   @ 194M   (col means, indexed by w)
//   xxa  f32  [16][2][256][64] @ 196M
//   xrct f32  [16][2][64][256] @ 198M  (position-major rc output)
//   wqkv bf16 [512][256] @ 200M ; wpw [256][512]; wpr [256][256]; bqkv f32[512]
// ---------------------------------------------------------------------------

typedef short s16x8 __attribute__((ext_vector_type(8)));
typedef short s16x4 __attribute__((ext_vector_type(4)));
typedef float f32x4 __attribute__((ext_vector_type(4)));

#define OFF_QKVS 0ULL
#define OFF_DWO  67108864ULL
#define OFF_XBF  167772160ULL
#define OFF_MR   201326592ULL
#define OFF_MC   203423744ULL
#define OFF_XXA  205520896ULL
#define OFF_XRCT 207618048ULL
#define OFF_WQKV 209715200ULL
#define OFF_WPW  209977344ULL
#define OFF_WPR  210239488ULL
#define OFF_BQKV 210370560ULL

__device__ __forceinline__ float bf2f(unsigned short u) {
  unsigned int x = ((unsigned int)u) << 16;
  return __builtin_bit_cast(float, x);
}
__device__ __forceinline__ unsigned short f2bf(float f) {
  unsigned int x = __builtin_bit_cast(unsigned int, f);
  x += 0x7fffu + ((x >> 16) & 1u);   // RNE, finite inputs
  return (unsigned short)(x >> 16);
}
__device__ __forceinline__ float relu6f(float v) { return fminf(fmaxf(v, 0.f), 6.f); }

// D = A*B + D (A rows -> D rows, B cols -> D cols; verified round 1/3)
__device__ __forceinline__ void mfma16(f32x4& d, s16x8 a, s16x8 b) {
  asm("v_mfma_f32_16x16x32_bf16 %0, %1, %2, %0" : "+v"(d) : "v"(a), "v"(b));
}

// ---------------------------------------------------------------------------
// prep: bid < 4096 -> x transpose tile; bid >= 4096 -> weight pack (verified r14)
// ---------------------------------------------------------------------------
__global__ __launch_bounds__(256) void prep_k(
    const float* __restrict__ x, unsigned short* __restrict__ xbf,
    const float* __restrict__ Wq, const float* __restrict__ Wk, const float* __restrict__ Wv,
    const float* __restrict__ bq, const float* __restrict__ bk, const float* __restrict__ bv,
    const float* __restrict__ Wpw, const float* __restrict__ Wpr,
    unsigned short* __restrict__ wqkv, unsigned short* __restrict__ wpw,
    unsigned short* __restrict__ wpr, float* __restrict__ bqkv)
{
  __shared__ float tile[64][68];
  const int bid = blockIdx.x;
  const int tid = threadIdx.x;
  if (bid < 4096) {
    const int nt = bid & 63, ct = (bid >> 6) & 3, b = bid >> 8;
    const int n0 = nt * 64, c0 = ct * 64;
    #pragma unroll
    for (int p = 0; p < 4; ++p) {
      const int g = tid + p * 256;
      const int row = g >> 4, ch = g & 15;
      const float4 v = *(const float4*)&x[((size_t)b * 256 + c0 + row) * 4096 + n0 + ch * 4];
      *(float4*)&tile[row][ch * 4] = v;
    }
    __syncthreads();
    #pragma unroll
    for (int p = 0; p < 2; ++p) {
      const int g = tid + p * 256;
      const int nr = g >> 3, cc = g & 7;
      s16x8 o;
      #pragma unroll
      for (int q = 0; q < 8; ++q) o[q] = f2bf(tile[cc * 8 + q][nr]);
      *(s16x8*)&xbf[((size_t)b * 4096 + n0 + nr) * 256 + c0 + cc * 8] = o;
    }
  } else {
    const int i = (bid - 4096) * 256 + tid;
    if (i < 131072) {
      const int o = i >> 8, k = i & 255;
      float v = (o < 128) ? Wq[o * 256 + k]
              : (o < 256) ? Wk[(o - 128) * 256 + k]
                          : Wv[(o - 256) * 256 + k];
      wqkv[i] = f2bf(v);
    } else if (i < 262144) {
      const int j = i - 131072;
      wpw[j] = f2bf(Wpw[j]);
    } else if (i < 327680) {
      const int j = i - 262144;
      wpr[j] = f2bf(Wpr[j]);
    } else if (i < 328192) {
      const int o = i - 327680;
      bqkv[o] = (o < 128) ? bq[o] : (o < 256) ? bk[o - 128] : bv[o - 256];
    }
  }
}

// ---------------------------------------------------------------------------
// GEMM staging into padded LDS [rows][72] (verified layout; used by fin_k)
// ---------------------------------------------------------------------------
template <int ROWS>
__device__ __forceinline__ void stage_rows(const unsigned short* __restrict__ src,
                                           int ld, unsigned short (*S)[72], int tid)
{
  #pragma unroll
  for (int p = 0; p < ROWS / 32; ++p) {
    const int g = tid + p * 256;
    const int r = g >> 3, sl = g & 7;
    *(s16x8*)&S[r][sl * 8] = *(const s16x8*)&src[(size_t)r * ld + sl * 8];
  }
}

// one 64-K step: acc[8][2] += W-subtile(128 o) x X-subtile(32 n)  (fin_k)
__device__ __forceinline__ void compute64(const unsigned short (*As)[72],
                                          const unsigned short (*Xs)[72],
                                          f32x4 (*acc)[2], int wm, int wn, int lane)
{
  #pragma unroll
  for (int ks = 0; ks < 64; ks += 32) {
    s16x8 bF[2], aF[8];
    #pragma unroll
    for (int j = 0; j < 2; ++j)
      bF[j] = *(const s16x8*)&Xs[wn * 32 + j * 16 + (lane & 15)][ks + (lane >> 4) * 8];
    #pragma unroll
    for (int i = 0; i < 8; ++i)
      aF[i] = *(const s16x8*)&As[wm * 128 + i * 16 + (lane & 15)][ks + (lane >> 4) * 8];
    #pragma unroll
    for (int i = 0; i < 8; ++i)
      #pragma unroll
      for (int j = 0; j < 2; ++j)
        mfma16(acc[i][j], aF[i], bF[j]);
  }
}

// ---------------------------------------------------------------------------
// QKV (verified round 9): W panel LDS-resident, 4 fat n-tiles, XOR swizzle,
// X reg-prefetch, in-wave row-mean.
// ---------------------------------------------------------------------------
__global__ __launch_bounds__(256, 2) void qkv_k(
    const unsigned short* __restrict__ wqkv, const float* __restrict__ bias,
    const unsigned short* __restrict__ xbf, unsigned short* __restrict__ qkvs,
    float* __restrict__ mr)
{
  __shared__ __align__(16) unsigned short Ws[128][256];  // swizzled granules
  __shared__ __align__(16) unsigned short Xs[128][64];   // swizzled granules
  const int tid = threadIdx.x, lane = tid & 63, wave = tid >> 6;
  const int wm = wave >> 1, wn = wave & 1;
  const int bid = blockIdx.x;
  const int ng = bid & 7, mt = (bid >> 3) & 3, b = bid >> 5;
  const int row0 = mt * 128;
  const int n_base = ng * 512;
  const unsigned short* Xb = xbf + ((size_t)b * 4096 + n_base) * 256;

  s16x8 pX[4];
  #pragma unroll
  for (int p = 0; p < 4; ++p) {
    const int g = tid + p * 256, r = g >> 3, gl = g & 7;
    pX[p] = *(const s16x8*)&Xb[(size_t)r * 256 + gl * 8];
  }
  #pragma unroll
  for (int p = 0; p < 16; ++p) {
    const int g = tid + p * 256;
    const int r = g >> 5, gl = g & 31;
    *(s16x8*)&Ws[r][(gl ^ (r & 7)) * 8] =
        *(const s16x8*)&wqkv[(size_t)(row0 + r) * 256 + gl * 8];
  }

  for (int t = 0; t < 4; ++t) {
    f32x4 acc[4][4];
    #pragma unroll
    for (int i = 0; i < 4; ++i)
      #pragma unroll
      for (int j = 0; j < 4; ++j) acc[i][j] = (f32x4){0.f, 0.f, 0.f, 0.f};

    #pragma unroll
    for (int c = 0; c < 4; ++c) {
      __syncthreads();
      #pragma unroll
      for (int p = 0; p < 4; ++p) {
        const int g = tid + p * 256, r = g >> 3, gl = g & 7;
        *(s16x8*)&Xs[r][(gl ^ (r & 7)) * 8] = pX[p];
      }
      __syncthreads();
      const int ci = t * 4 + c;
      if (ci < 15) {
        const int tn = (ci + 1) >> 2, cn = (ci + 1) & 3;
        #pragma unroll
        for (int p = 0; p < 4; ++p) {
          const int g = tid + p * 256, r = g >> 3, gl = g & 7;
          pX[p] = *(const s16x8*)&Xb[(size_t)(tn * 128 + r) * 256 + cn * 64 + gl * 8];
        }
      }
      #pragma unroll
      for (int ks = 0; ks < 64; ks += 32) {
        s16x8 aF[4], bF[4];
        #pragma unroll
        for (int i = 0; i < 4; ++i) {
          const int row = wm * 64 + i * 16 + (lane & 15);
          const int kg = ((c * 64 + ks) >> 3) + (lane >> 4);
          aF[i] = *(const s16x8*)&Ws[row][(kg ^ (row & 7)) * 8];
        }
        #pragma unroll
        for (int j = 0; j < 4; ++j) {
          const int row = wn * 64 + j * 16 + (lane & 15);
          const int kg = (ks >> 3) + (lane >> 4);
          bF[j] = *(const s16x8*)&Xs[row][(kg ^ (row & 7)) * 8];
        }
        #pragma unroll
        for (int i = 0; i < 4; ++i)
          #pragma unroll
          for (int j = 0; j < 4; ++j)
            mfma16(acc[i][j], aF[i], bF[j]);
      }
    }

    const int n0 = n_base + t * 128;
    #pragma unroll
    for (int i = 0; i < 4; ++i) {
      const int o0 = row0 + wm * 64 + i * 16 + ((lane >> 4) << 2);
      const float4 b4 = *(const float4*)&bias[o0];
      const float bv[4] = {b4.x, b4.y, b4.z, b4.w};
      #pragma unroll
      for (int j = 0; j < 4; ++j) {
        const int n = n0 + wn * 64 + j * 16 + (lane & 15);
        s16x4 pk;
        pk[0] = f2bf(acc[i][j][0] + bv[0]);
        pk[1] = f2bf(acc[i][j][1] + bv[1]);
        pk[2] = f2bf(acc[i][j][2] + bv[2]);
        pk[3] = f2bf(acc[i][j][3] + bv[3]);
        *(s16x4*)&qkvs[((size_t)b * 4096 + n) * 512 + o0] = pk;
      }
      #pragma unroll
      for (int r = 0; r < 4; ++r) {
        float s = acc[i][0][r] + acc[i][1][r] + acc[i][2][r] + acc[i][3][r];
        s += __shfl_xor(s, 1);
        s += __shfl_xor(s, 2);
        s += __shfl_xor(s, 4);
        s += __shfl_xor(s, 8);
        if ((lane & 15) == 0) {
          const int o = o0 + r;
          mr[((size_t)b * 512 + o) * 64 + (n0 >> 6) + wn] = s * (1.f / 64.f) + bv[r];
        }
      }
    }
  }
}

// ---------------------------------------------------------------------------
// dwm (verified r5 math) + mc (verified r11), 256-thread blocks.
// bid < 2048: dwm: b = bid>>7, h = (bid>>1)&63, whalf = bid&1;
//   thread: c0 = (tid&63)*8, w0 = ((whalf*4) + (tid>>6))*8  (4 strips/block)
// bid >= 2048: mc block mbid = bid-2048 (verbatim r11).
// ---------------------------------------------------------------------------
__global__ __launch_bounds__(256, 2) void dwmmc_k(
    const unsigned short* __restrict__ qkvs, const float* __restrict__ Wdw,
    const float* __restrict__ bdw, unsigned short* __restrict__ dwo,
    float* __restrict__ mc)
{
  const int bid = blockIdx.x;
  const int tid = threadIdx.x;
  if (bid < 2048) {                       // ---- dwm ----
    const int b = bid >> 7;
    const int h = (bid >> 1) & 63;
    const int whalf = bid & 1;
    const int c0 = (tid & 63) * 8;
    const int w0 = (whalf * 4 + (tid >> 6)) * 8;
    float w9[8][9], bs[8];
    #pragma unroll
    for (int q = 0; q < 8; ++q) {
      bs[q] = bdw[c0 + q];
      #pragma unroll
      for (int j = 0; j < 9; ++j) w9[q][j] = Wdw[(c0 + q) * 9 + j];
    }
    float acc[8][8];
    #pragma unroll
    for (int w = 0; w < 8; ++w)
      #pragma unroll
      for (int q = 0; q < 8; ++q) acc[w][q] = bs[q];

    const size_t base = (size_t)b * 4096 * 512;
    #pragma unroll
    for (int dr = 0; dr < 3; ++dr) {
      const int hh = h + dr - 1;
      if ((unsigned)hh < 64u) {
        s16x8 rowd[10];
        #pragma unroll
        for (int t = 0; t < 10; ++t) {
          const int ww = w0 + t - 1;
          if ((unsigned)ww < 64u)
            rowd[t] = *(const s16x8*)&qkvs[base + (size_t)(hh * 64 + ww) * 512 + c0];
          else
            rowd[t] = (s16x8){0, 0, 0, 0, 0, 0, 0, 0};
        }
        #pragma unroll
        for (int t = 0; t < 10; ++t) {
          float fv[8];
          #pragma unroll
          for (int q = 0; q < 8; ++q) fv[q] = bf2f((unsigned short)rowd[t][q]);
          #pragma unroll
          for (int dc = 0; dc < 3; ++dc) {
            const int w = t - dc;
            if (w >= 0 && w < 8) {
              #pragma unroll
              for (int q = 0; q < 8; ++q)
                acc[w][q] += w9[q][dr * 3 + dc] * fv[q];
            }
          }
        }
      }
    }
    #pragma unroll
    for (int w = 0; w < 8; ++w) {
      s16x8 o8;
      #pragma unroll
      for (int q = 0; q < 8; ++q) o8[q] = f2bf(relu6f(acc[w][q]));
      *(s16x8*)&dwo[base + (size_t)(h * 64 + w0 + w) * 512 + c0] = o8;
    }
  } else {                                // ---- mc (verbatim r11) ----
    const int mbid = bid - 2048;          // 0..255
    const int posq = mbid & 15, b = mbid >> 4;
    const int c0 = (tid & 63) * 8;
    const int pos = posq * 4 + (tid >> 6);
    float s[8] = {0.f, 0.f, 0.f, 0.f, 0.f, 0.f, 0.f, 0.f};
    for (int t = 0; t < 64; ++t) {
      const s16x8 v = *(const s16x8*)&qkvs[((size_t)b * 4096 + t * 64 + pos) * 512 + c0];
      #pragma unroll
      for (int q = 0; q < 8; ++q) s[q] += bf2f((unsigned short)v[q]);
    }
    #pragma unroll
    for (int q = 0; q < 8; ++q)
      mc[((size_t)b * 512 + c0 + q) * 64 + pos] = s[q] * (1.f / 64.f);
  }
}

// ---------------------------------------------------------------------------
// fused final (round-7 verified): pw = Wpw.dwo+bpw ; pr = Wpr.relu6(v+xr+xc)+bpr
// out[o][n] = h_sig(pr)*pw. T14 prefetch of X (loop 1) and v (loop 2).
// ---------------------------------------------------------------------------
__global__ __launch_bounds__(256, 2) void fin_k(
    const unsigned short* __restrict__ wpw, const float* __restrict__ bpw,
    const unsigned short* __restrict__ wpr, const float* __restrict__ bpr,
    const unsigned short* __restrict__ dwo, const unsigned short* __restrict__ qkvs,
    const float* __restrict__ xrct, float* __restrict__ out)
{
  __shared__ __align__(16) unsigned short As[256][72];
  __shared__ __align__(16) unsigned short Xs[64][72];
  const int tid = threadIdx.x, lane = tid & 63, wave = tid >> 6;
  const int wm = wave >> 1, wn = wave & 1;
  const int bid = blockIdx.x;
  const int nt = bid & 63, b = bid >> 6;
  const int col0 = nt * 64;                 // h = nt, w = n-local

  f32x4 apw[8][2], apr[8][2];
  #pragma unroll
  for (int i = 0; i < 8; ++i)
    #pragma unroll
    for (int j = 0; j < 2; ++j) {
      apw[i][j] = (f32x4){0.f, 0.f, 0.f, 0.f};
      apr[i][j] = (f32x4){0.f, 0.f, 0.f, 0.f};
    }

  // ---- GEMM 1: pw = Wpw . dwo, K = 512, X prefetched ----
  const unsigned short* Xb1 = dwo + ((size_t)b * 4096 + col0) * 512;
  s16x8 pX[2];
  #pragma unroll
  for (int p = 0; p < 2; ++p) {
    const int g = tid + p * 256, r = g >> 3, sl = g & 7;
    pX[p] = *(const s16x8*)&Xb1[(size_t)r * 512 + sl * 8];
  }
  for (int k0 = 0; k0 < 512; k0 += 64) {
    stage_rows<256>(wpw + k0, 512, As, tid);       // W panel: L2-hot
    #pragma unroll
    for (int p = 0; p < 2; ++p) {
      const int g = tid + p * 256, r = g >> 3, sl = g & 7;
      *(s16x8*)&Xs[r][sl * 8] = pX[p];
    }
    __syncthreads();
    if (k0 + 64 < 512) {
      const int kn = k0 + 64;
      #pragma unroll
      for (int p = 0; p < 2; ++p) {
        const int g = tid + p * 256, r = g >> 3, sl = g & 7;
        pX[p] = *(const s16x8*)&Xb1[(size_t)r * 512 + kn + sl * 8];
      }
    }
    compute64(As, Xs, apw, wm, wn, lane);
    __syncthreads();
  }

  // ---- GEMM 2: pr = Wpr . relu6(v + xr + xc), K = 256, v prefetched ----
  const float* xr = &xrct[(((size_t)b * 2 + 0) * 64 + nt) * 256];   // block-uniform h
  const float* xc = &xrct[(((size_t)b * 2 + 1) * 64) * 256];
  const unsigned short* Vb = qkvs + ((size_t)b * 4096 + col0) * 512 + 256;
  s16x8 pV[2];
  #pragma unroll
  for (int p = 0; p < 2; ++p) {
    const int g = tid + p * 256, r = g >> 3, sl = g & 7;
    pV[p] = *(const s16x8*)&Vb[(size_t)r * 512 + sl * 8];
  }
  for (int k0 = 0; k0 < 256; k0 += 64) {
    stage_rows<256>(wpr + k0, 256, As, tid);
    #pragma unroll
    for (int p = 0; p < 2; ++p) {
      const int g = tid + p * 256, r = g >> 3, sl = g & 7;
      const int kk = k0 + sl * 8;
      const float4 a0 = *(const float4*)&xr[kk];
      const float4 a1 = *(const float4*)&xr[kk + 4];
      const float4 c0v = *(const float4*)&xc[(size_t)r * 256 + kk];
      const float4 c1v = *(const float4*)&xc[(size_t)r * 256 + kk + 4];
      const float ar[8] = {a0.x, a0.y, a0.z, a0.w, a1.x, a1.y, a1.z, a1.w};
      const float ac[8] = {c0v.x, c0v.y, c0v.z, c0v.w, c1v.x, c1v.y, c1v.z, c1v.w};
      s16x8 o;
      #pragma unroll
      for (int q = 0; q < 8; ++q)
        o[q] = f2bf(relu6f(bf2f((unsigned short)pV[p][q]) + ar[q] + ac[q]));
      *(s16x8*)&Xs[r][sl * 8] = o;
    }
    __syncthreads();
    if (k0 + 64 < 256) {
      const int kn = k0 + 64;
      #pragma unroll
      for (int p = 0; p < 2; ++p) {
        const int g = tid + p * 256, r = g >> 3, sl = g & 7;
        pV[p] = *(const s16x8*)&Vb[(size_t)r * 512 + kn + sl * 8];
      }
    }
    compute64(As, Xs, apr, wm, wn, lane);
    __syncthreads();
  }

  #pragma unroll
  for (int i = 0; i < 8; ++i) {
    const int o0 = wm * 128 + i * 16 + ((lane >> 4) << 2);
    const float4 bw = *(const float4*)&bpw[o0];
    const float4 bp = *(const float4*)&bpr[o0];
    const float bwv[4] = {bw.x, bw.y, bw.z, bw.w};
    const float bpv[4] = {bp.x, bp.y, bp.z, bp.w};
    #pragma unroll
    for (int j = 0; j < 2; ++j) {
      const int n = col0 + wn * 32 + j * 16 + (lane & 15);
      #pragma unroll
      for (int r = 0; r < 4; ++r) {
        const float hs = fminf(fmaxf(apr[i][j][r] + bpv[r] + 3.f, 0.f), 6.f) * (1.f / 6.f);
        out[((size_t)b * 256 + o0 + r) * 4096 + n] = hs * (apw[i][j][r] + bwv[r]);
      }
    }
  }
}

// ---------------------------------------------------------------------------
// axial attention (verified)
// ---------------------------------------------------------------------------
__global__ __launch_bounds__(256) void attn_k(
    const float* __restrict__ mr, const float* __restrict__ mc,
    const float* __restrict__ pe_rq, const float* __restrict__ pe_rk,
    const float* __restrict__ pe_cq, const float* __restrict__ pe_ck,
    float* __restrict__ xxa)
{
  __shared__ float qh[16][69], kh[16][69], vh[32][69], P[64][69];
  const int bid = blockIdx.x;
  const int hd = bid & 7, axis = (bid >> 3) & 1, b = bid >> 4;
  const float* m  = axis ? mc : mr;
  const float* pq = axis ? pe_cq : pe_rq;
  const float* pk = axis ? pe_ck : pe_rk;
  const int tid = threadIdx.x;

  #pragma unroll
  for (int p = 0; p < 4; ++p) {
    const int e = tid + p * 256;
    const int kd = e >> 6, i = e & 63;
    float srcp = 0.25f * (float)i - 0.375f;
    srcp = fminf(fmaxf(srcp, 0.f), 15.f);
    const int lo = (int)srcp;
    const int hi = min(lo + 1, 15);
    const float w = srcp - (float)lo;
    const int cq = hd * 16 + kd;
    qh[kd][i] = m[((size_t)b * 512 + cq) * 64 + i]
              + pq[cq * 16 + lo] * (1.f - w) + pq[cq * 16 + hi] * w;
    kh[kd][i] = m[((size_t)b * 512 + 128 + cq) * 64 + i]
              + pk[cq * 16 + lo] * (1.f - w) + pk[cq * 16 + hi] * w;
  }
  #pragma unroll
  for (int p = 0; p < 8; ++p) {
    const int e = tid + p * 256;
    const int d = e >> 6, j = e & 63;
    vh[d][j] = m[((size_t)b * 512 + 256 + hd * 32 + d) * 64 + j];
  }
  __syncthreads();
  {
    const int i = tid >> 2, j0 = (tid & 3) * 16;
    float qr[16];
    #pragma unroll
    for (int kd = 0; kd < 16; ++kd) qr[kd] = qh[kd][i];
    #pragma unroll
    for (int jj = 0; jj < 16; ++jj) {
      float s = 0.f;
      #pragma unroll
      for (int kd = 0; kd < 16; ++kd) s += qr[kd] * kh[kd][j0 + jj];
      P[i][j0 + jj] = s * 0.25f;
    }
  }
  __syncthreads();
  if (tid < 64) {
    float mx = -1e30f;
    for (int j = 0; j < 64; ++j) mx = fmaxf(mx, P[tid][j]);
    float sum = 0.f;
    for (int j = 0; j < 64; ++j) { const float e = __expf(P[tid][j] - mx); P[tid][j] = e; sum += e; }
    const float inv = 1.f / sum;
    for (int j = 0; j < 64; ++j) P[tid][j] *= inv;
  }
  __syncthreads();
  #pragma unroll
  for (int p = 0; p < 8; ++p) {
    const int e = tid + p * 256;
    const int d = e >> 6, i = e & 63;
    float s = 0.f;
    for (int j = 0; j < 64; ++j) s += P[i][j] * vh[d][j];
    xxa[(((size_t)(b * 2 + axis)) * 256 + hd * 32 + d) * 64 + i] = s;
  }
}

// ---------------------------------------------------------------------------
// xrct[b][axis][pos][o] = (W_row/W_col @ relu6(xxa))[o][pos] + bias[o]
// ---------------------------------------------------------------------------
__global__ __launch_bounds__(256) void rc_k(
    const float* __restrict__ xxa, const float* __restrict__ Wrow, const float* __restrict__ brow,
    const float* __restrict__ Wcol, const float* __restrict__ bcol, float* __restrict__ xrct)
{
  __shared__ float stf[256][8];
  const int bid = blockIdx.x;
  const int ic = bid & 7, axis = (bid >> 3) & 1, b = bid >> 4;
  const float* W  = axis ? Wcol : Wrow;
  const float* bi = axis ? bcol : brow;
  const int tid = threadIdx.x;
  {
    const float* srcp = xxa + (((size_t)(b * 2 + axis)) * 256 + tid) * 64 + ic * 8;
    #pragma unroll
    for (int q = 0; q < 8; ++q) stf[tid][q] = relu6f(srcp[q]);
  }
  __syncthreads();
  float acc[8] = {0.f, 0.f, 0.f, 0.f, 0.f, 0.f, 0.f, 0.f};
  for (int c = 0; c < 256; ++c) {
    const float w = W[tid * 256 + c];
    const float4 s0 = *(const float4*)&stf[c][0];
    const float4 s1 = *(const float4*)&stf[c][4];
    acc[0] += w * s0.x; acc[1] += w * s0.y; acc[2] += w * s0.z; acc[3] += w * s0.w;
    acc[4] += w * s1.x; acc[5] += w * s1.y; acc[6] += w * s1.z; acc[7] += w * s1.w;
  }
  const float bb = bi[tid];
  #pragma unroll
  for (int q = 0; q < 8; ++q)
    xrct[(((size_t)(b * 2 + axis)) * 64 + ic * 8 + q) * 256 + tid] = acc[q] + bb;
}

// ---------------------------------------------------------------------------
extern "C" void kernel_launch(void* const* d_in, const int* in_sizes, int n_in,
                              void* d_out, int out_size, void* d_ws, size_t ws_size,
                              hipStream_t stream)
{
  const float* x    = (const float*)d_in[0];
  const float* Wq   = (const float*)d_in[1];
  const float* bq   = (const float*)d_in[2];
  const float* Wk   = (const float*)d_in[3];
  const float* bk   = (const float*)d_in[4];
  const float* Wv   = (const float*)d_in[5];
  const float* bv   = (const float*)d_in[6];
  const float* Wdw  = (const float*)d_in[7];
  const float* bdw  = (const float*)d_in[8];
  const float* Wpw  = (const float*)d_in[9];
  const float* bpw  = (const float*)d_in[10];
  const float* Wrow = (const float*)d_in[11];
  const float* brow = (const float*)d_in[12];
  const float* Wcol = (const float*)d_in[13];
  const float* bcol = (const float*)d_in[14];
  const float* Wpr  = (const float*)d_in[15];
  const float* bpr  = (const float*)d_in[16];
  const float* perq = (const float*)d_in[17];
  const float* perk = (const float*)d_in[18];
  const float* pecq = (const float*)d_in[19];
  const float* peck = (const float*)d_in[20];

  char* ws = (char*)d_ws;
  unsigned short* qkvs = (unsigned short*)(ws + OFF_QKVS);
  unsigned short* dwo  = (unsigned short*)(ws + OFF_DWO);
  unsigned short* xbf  = (unsigned short*)(ws + OFF_XBF);
  float* mr   = (float*)(ws + OFF_MR);
  float* mc   = (float*)(ws + OFF_MC);
  float* xxa  = (float*)(ws + OFF_XXA);
  float* xrct = (float*)(ws + OFF_XRCT);
  unsigned short* wqkv = (unsigned short*)(ws + OFF_WQKV);
  unsigned short* wpw  = (unsigned short*)(ws + OFF_WPW);
  unsigned short* wpr  = (unsigned short*)(ws + OFF_WPR);
  float* bqkv = (float*)(ws + OFF_BQKV);

  prep_k<<<5378, 256, 0, stream>>>(x, xbf, Wq, Wk, Wv, bq, bk, bv, Wpw, Wpr,
                                   wqkv, wpw, wpr, bqkv);

  qkv_k<<<512, 256, 0, stream>>>(wqkv, bqkv, xbf, qkvs, mr);
  dwmmc_k<<<2304, 256, 0, stream>>>(qkvs, Wdw, bdw, dwo, mc);
  attn_k<<<256, 256, 0, stream>>>(mr, mc, perq, perk, pecq, peck, xxa);
  rc_k<<<256, 256, 0, stream>>>(xxa, Wrow, brow, Wcol, bcol, xrct);
  fin_k<<<1024, 256, 0, stream>>>(wpw, bpw, wpr, bpr, dwo, qkvs, xrct, (float*)d_out);
}